// Round 1
// baseline (85.166 us; speedup 1.0000x reference)
//
#include <hip/hip_runtime.h>
#include <math.h>

// MAM dense: C[i,j] = max_k(A[i,k]*W[j,k]) + min_k(A[i,k]*W[j,k]) + bias[j]
// A = x flattened [M=2048, K=768]; W = weight [N=768, K=768]; out [M, N] f32.
// Pure VALU kernel (no fp32 MFMA exists; max/min reductions can't use MFMA).

#define M_DIM 2048
#define N_DIM 768
#define K_DIM 768

#define BM 64
#define BN 32
#define BK 32
#define TM 4
#define TN 2
// 256 threads: 16 (m-dir) x 16 (n-dir); grid = (768/32) x (2048/64) = 24 x 32 = 768 blocks = 3/CU

__global__ __launch_bounds__(256, 3) void mam_kernel(
    const float* __restrict__ A, const float* __restrict__ W,
    const float* __restrict__ bias, float* __restrict__ out)
{
    // A-tile transposed [k][m], pad +4 to keep 16B row alignment for ds_read_b128
    __shared__ float As[BK][BM + 4];
    // B-tile [k][n], pad +2 keeps 8B alignment for ds_read_b64
    __shared__ float Bs[BK][BN + 2];

    const int tid = threadIdx.x;
    const int m0 = blockIdx.y * BM;
    const int n0 = blockIdx.x * BN;
    const int mt = tid >> 4;   // 0..15, m-dir thread index
    const int nt = tid & 15;   // 0..15, n-dir thread index

    float amax[TM][TN], amin[TM][TN];
#pragma unroll
    for (int i = 0; i < TM; ++i)
#pragma unroll
        for (int j = 0; j < TN; ++j) {
            amax[i][j] = -INFINITY;
            amin[i][j] =  INFINITY;
        }

    // staging assignments
    const int ar = tid >> 2;        // 0..63  : A row within tile
    const int ac = (tid & 3) * 8;   // 0,8,16,24 : A k-offset (8 floats each)
    const int br = tid >> 3;        // 0..31  : W row (j) within tile
    const int bc = (tid & 7) * 4;   // 0..28  : W k-offset (4 floats each)

    const float* Ap = A + (size_t)(m0 + ar) * K_DIM + ac;
    const float* Wp = W + (size_t)(n0 + br) * K_DIM + bc;

    for (int k0 = 0; k0 < K_DIM; k0 += BK) {
        // global loads first (start early, overlap with barrier)
        const float4 av0 = *(const float4*)(Ap + k0);
        const float4 av1 = *(const float4*)(Ap + k0 + 4);
        const float4 bv  = *(const float4*)(Wp + k0);

        __syncthreads();   // previous tile's reads complete before overwrite

        As[ac + 0][ar] = av0.x; As[ac + 1][ar] = av0.y;
        As[ac + 2][ar] = av0.z; As[ac + 3][ar] = av0.w;
        As[ac + 4][ar] = av1.x; As[ac + 5][ar] = av1.y;
        As[ac + 6][ar] = av1.z; As[ac + 7][ar] = av1.w;

        Bs[bc + 0][br] = bv.x; Bs[bc + 1][br] = bv.y;
        Bs[bc + 2][br] = bv.z; Bs[bc + 3][br] = bv.w;

        __syncthreads();

#pragma unroll
        for (int kk = 0; kk < BK; kk += 2) {
            const float4 a0 = *(const float4*)&As[kk][mt * TM];
            const float4 a1 = *(const float4*)&As[kk + 1][mt * TM];
            const float2 b0 = *(const float2*)&Bs[kk][nt * TN];
            const float2 b1 = *(const float2*)&Bs[kk + 1][nt * TN];
            const float a0a[TM] = {a0.x, a0.y, a0.z, a0.w};
            const float a1a[TM] = {a1.x, a1.y, a1.z, a1.w};
            const float b0a[TN] = {b0.x, b0.y};
            const float b1a[TN] = {b1.x, b1.y};
#pragma unroll
            for (int i = 0; i < TM; ++i)
#pragma unroll
                for (int j = 0; j < TN; ++j) {
                    const float p0 = a0a[i] * b0a[j];
                    const float p1 = a1a[i] * b1a[j];
                    // hope: clang fuses nested fmaxf/fminf into v_max3_f32 / v_min3_f32
                    amax[i][j] = fmaxf(amax[i][j], fmaxf(p0, p1));
                    amin[i][j] = fminf(amin[i][j], fminf(p0, p1));
                }
        }
    }

    const float bv0 = bias[n0 + nt * TN + 0];
    const float bv1 = bias[n0 + nt * TN + 1];
#pragma unroll
    for (int i = 0; i < TM; ++i) {
        float2 o;
        o.x = amax[i][0] + amin[i][0] + bv0;
        o.y = amax[i][1] + amin[i][1] + bv1;
        *(float2*)&out[(size_t)(m0 + mt * TM + i) * N_DIM + n0 + nt * TN] = o;
    }
}

extern "C" void kernel_launch(void* const* d_in, const int* in_sizes, int n_in,
                              void* d_out, int out_size, void* d_ws, size_t ws_size,
                              hipStream_t stream) {
    const float* x    = (const float*)d_in[0];   // [2,1024,768] -> [2048,768]
    const float* w    = (const float*)d_in[1];   // [768,768] row-major [N][K]
    const float* bias = (const float*)d_in[2];   // [768]
    float* out = (float*)d_out;                  // [2048,768]

    dim3 grid(N_DIM / BN, M_DIM / BM);           // (24, 32) = 768 blocks
    mam_kernel<<<grid, 256, 0, stream>>>(x, w, bias, out);
}